// Round 12
// baseline (2347.600 us; speedup 1.0000x reference)
//
#include <hip/hip_runtime.h>
#include <math.h>

#define BB 2
#define CCH 64
#define NN 4096
#define KK 9
#define TT 2
#define C2 128
#define C4 256
#define R1 (BB*NN)        /* 8192  */
#define RG (BB*NN*KK)     /* 73728 */
#define SPLIT 16
#define CHUNK (NN/SPLIT)  /* 256 */
#define JT 64             /* j-tile rows staged in LDS */

#define WS_TOTAL 5194240ull

__device__ __forceinline__ float gelu(float v){ return 0.5f*v*(1.f + erff(v*0.70710678118654752f)); }

__global__ void k_zero(float* __restrict__ o, int n){
  int i = blockIdx.x*256 + threadIdx.x;
  if (i < n) o[i] = 0.f;
}

// ---------------- transpose x (B,C,N) -> x0f (B,N,C) ----------------
__global__ void k_transpose(const float* __restrict__ x, float* __restrict__ x0f){
  int idx = blockIdx.x*256 + threadIdx.x;
  if (idx >= BB*NN*CCH) return;
  int c = idx & (CCH-1);
  int n = (idx >> 6) & (NN-1);
  int b = idx >> 18;
  x0f[idx] = x[(size_t)(b*CCH + c)*NN + n];
}

// ---------------- GEMM1 (64->64) + stats: 512 blocks x 16 rows ----------------
__global__ void k_gemm1_stats(const float* __restrict__ X, const float* __restrict__ W,
                              const float* __restrict__ bias, float* __restrict__ Y,
                              float* __restrict__ part){
  __shared__ float WL[64*64];
  __shared__ float xL[16*64];
  __shared__ float s1[256], s2[256];
  int tid = threadIdx.x;
  int r0 = blockIdx.x*16;
  {
    const float4* ws4 = (const float4*)W;
    float4* wd4 = (float4*)WL;
    #pragma unroll
    for (int u=0; u<4; u++) wd4[u*256+tid] = ws4[u*256+tid];
    ((float4*)xL)[tid] = ((const float4*)(X + (size_t)r0*64))[tid];
  }
  __syncthreads();
  int c = tid & 63, rs = tid >> 6;
  float bz = bias[c];
  float sm=0.f, ss=0.f;
  for (int it=0; it<4; it++){
    int lr = it*4 + rs;
    float acc = bz;
    for (int d=0; d<64; d++) acc = fmaf(xL[lr*64+d], WL[d*64+c], acc);
    Y[(size_t)(r0+lr)*64 + c] = acc;
    sm += acc; ss += acc*acc;
  }
  s1[tid]=sm; s2[tid]=ss;
  __syncthreads();
  if (tid < 64){
    sm = s1[tid]+s1[64+tid]+s1[128+tid]+s1[192+tid];
    ss = s2[tid]+s2[64+tid]+s2[128+tid]+s2[192+tid];
    part[blockIdx.x*128 + tid] = sm;
    part[blockIdx.x*128 + 64 + tid] = ss;
  }
}

// ---------------- GEMM2 (128->64) + stats: 512 blocks x 16 rows ----------------
__global__ void k_gemm2_stats(const float* __restrict__ X, const float* __restrict__ W,
                              const float* __restrict__ bias, float* __restrict__ Y,
                              float* __restrict__ part){
  __shared__ float WL[128*64];
  __shared__ float xL[16*128];
  __shared__ float s1[256], s2[256];
  int tid = threadIdx.x;
  int r0 = blockIdx.x*16;
  {
    const float4* ws4 = (const float4*)W;
    float4* wd4 = (float4*)WL;
    #pragma unroll
    for (int u=0; u<8; u++) wd4[u*256+tid] = ws4[u*256+tid];
    const float4* xs4 = (const float4*)(X + (size_t)r0*128);
    float4* xd4 = (float4*)xL;
    #pragma unroll
    for (int u=0; u<2; u++) xd4[u*256+tid] = xs4[u*256+tid];
  }
  __syncthreads();
  int c = tid & 63, rs = tid >> 6;
  float bz = bias[c];
  float sm=0.f, ss=0.f;
  for (int it=0; it<4; it++){
    int lr = it*4 + rs;
    float acc = bz;
    for (int d=0; d<128; d++) acc = fmaf(xL[lr*128+d], WL[d*64+c], acc);
    Y[(size_t)(r0+lr)*64 + c] = acc;
    sm += acc; ss += acc*acc;
  }
  s1[tid]=sm; s2[tid]=ss;
  __syncthreads();
  if (tid < 64){
    sm = s1[tid]+s1[64+tid]+s1[128+tid]+s1[192+tid];
    ss = s2[tid]+s2[64+tid]+s2[128+tid]+s2[192+tid];
    part[blockIdx.x*128 + tid] = sm;
    part[blockIdx.x*128 + 64 + tid] = ss;
  }
}

// ------- generic BN finalize: 256 threads, slice-parallel over G partial blocks -------
__global__ void k_finalize256(const float* __restrict__ part, int G, int Cc,
                              const float* __restrict__ g, const float* __restrict__ bt,
                              float Rf, float* __restrict__ scsh){
  __shared__ float s1[256], s2[256];
  int tid = threadIdx.x;
  int S = 256 / Cc;
  int c = tid % Cc, sl = tid / Cc;
  int per = G / S;
  float sm=0.f, ss=0.f;
  int u0 = sl*per, u1 = u0 + per;
  #pragma unroll 4
  for (int u=u0; u<u1; u++){
    sm += part[u*2*Cc + c];
    ss += part[u*2*Cc + Cc + c];
  }
  s1[tid]=sm; s2[tid]=ss;
  __syncthreads();
  if (tid < Cc){
    for (int q=1; q<S; q++){ sm += s1[tid+q*Cc]; ss += s2[tid+q*Cc]; }
    float mean = sm/Rf;
    float var = fmaxf(ss/Rf - mean*mean, 0.f);
    float sc = g[tid]*rsqrtf(var+1e-5f);
    scsh[tid] = sc;
    scsh[Cc+tid] = bt[tid] - mean*sc;
  }
}

// ---------------- BN apply + row-normalize: 512 blocks x 16 rows ----------------
__global__ void k_applynorm2(float* __restrict__ h, const float* __restrict__ scsh,
                             float* __restrict__ xn, float* __restrict__ sq){
  __shared__ float scshL[128];
  int tid = threadIdx.x;
  if (tid < 128) scshL[tid] = scsh[tid];
  __syncthreads();
  int lane = tid & 63, w = tid >> 6;
  int r0 = blockIdx.x*16;
  for (int it=0; it<4; it++){
    int r = r0 + w*4 + it;
    float v = fmaf(h[(size_t)r*64+lane], scshL[lane], scshL[64+lane]);
    h[(size_t)r*64+lane] = v;
    float s2v = v*v;
    #pragma unroll
    for (int off=32; off; off>>=1) s2v += __shfl_xor(s2v, off, 64);
    float den = fmaxf(sqrtf(s2v), 1e-12f);
    float xv = v/den;
    xn[(size_t)r*64+lane] = xv;
    float t2 = xv*xv;
    #pragma unroll
    for (int off=32; off; off>>=1) t2 += __shfl_xor(t2, off, 64);
    if (lane==0) sq[r] = t2;
  }
}

// ---------------- top-9 streaming insert (strict <; j ascending in chunk) ----------
__device__ __forceinline__ void topk_insert(float d, int j, float* bd, int* bi,
                                            float& wd, int& wi){
  if (d < wd){
    bool done=false;
    #pragma unroll
    for (int q=0;q<9;q++){
      if (!done && bd[q]==wd && bi[q]==wi){ bd[q]=d; bi[q]=j; done=true; }
    }
    wd = bd[0]; wi = bi[0];
    #pragma unroll
    for (int q=1;q<9;q++){
      if (bd[q] > wd || (bd[q]==wd && bi[q] > wi)){ wd=bd[q]; wi=bi[q]; }
    }
  }
}

// ---------------- KNN: 1 i-row/thread (unchanged structure) ----------------
__global__ __launch_bounds__(256, 2) void k_knn(const float* __restrict__ xn,
                      const float* __restrict__ sq,
                      float* __restrict__ pd, int* __restrict__ pi_){
  __shared__ float xjL[JT*64];
  __shared__ float sqL[JT];
  int bx = blockIdx.x;
  if (bx >= 512) return;
  int b     = bx >> 8;
  int ib    = (bx >> 4) & 15;
  int split = bx & 15;
  int tid = threadIdx.x;
  const float* xb = xn + (size_t)b*NN*64;
  const float* sqb = sq + (size_t)b*NN;
  int i = ib*256 + tid;
  float4 xi[16];
  {
    const float4* p = (const float4*)(xb + (size_t)i*64);
    #pragma unroll
    for (int q=0;q<16;q++) xi[q] = p[q];
  }
  #pragma unroll
  for (int q=0;q<16;q++){
    asm volatile("" : "+v"(xi[q].x), "+v"(xi[q].y), "+v"(xi[q].z), "+v"(xi[q].w));
  }
  float sqi = sqb[i];
  float bd[9]; int bi[9];
  #pragma unroll
  for (int q=0;q<9;q++){ bd[q]=INFINITY; bi[q]=0x7fffffff; }
  float wd=INFINITY; int wi=0x7fffffff;
  int jbase = split*CHUNK;
  for (int tile=0; tile<CHUNK/JT; tile++){
    int jt = jbase + tile*JT;
    __syncthreads();
    {
      const float4* src = (const float4*)(xb + (size_t)jt*64);
      float4* dst = (float4*)xjL;
      #pragma unroll
      for (int u=0; u<4; u++) dst[u*256 + tid] = src[u*256 + tid];
      if (tid < JT) sqL[tid] = sqb[jt + tid];
    }
    __syncthreads();
    for (int jj=0; jj<JT; jj++){
      const float4* xj = (const float4*)(xjL + jj*64);
      float a0=0.f,a1=0.f,a2=0.f,a3=0.f;
      #pragma unroll
      for (int q=0;q<16;q++){
        float4 v = xj[q];
        a0 = fmaf(xi[q].x, v.x, a0);
        a1 = fmaf(xi[q].y, v.y, a1);
        a2 = fmaf(xi[q].z, v.z, a2);
        a3 = fmaf(xi[q].w, v.w, a3);
      }
      float dot = (a0+a1)+(a2+a3);
      int j = jt + jj;
      float d = sqi + sqL[jj] - 2.f*dot;
      topk_insert(d, j, bd, bi, wd, wi);
    }
  }
  size_t base = (((size_t)(b*NN + i))*SPLIT + split)*9;
  #pragma unroll
  for (int q=0;q<9;q++){ pd[base+q]=bd[q]; pi_[base+q]=bi[q]; }
}

// ---------------- merge: one WAVE per row; 144 distinct candidates -> 9 smallest ----
__global__ void k_knnmerge(const float* __restrict__ pd, const int* __restrict__ pi_,
                           int* __restrict__ idxf){
  int lane = threadIdx.x & 63;
  int row = blockIdx.x*4 + (threadIdx.x >> 6);
  if (row >= R1) return;
  size_t base = (size_t)row * (SPLIT*9);
  float d0, d1, d2 = INFINITY;
  int   j0, j1, j2 = 0x7fffffff;
  d0 = pd[base + lane];        j0 = pi_[base + lane];
  d1 = pd[base + 64 + lane];   j1 = pi_[base + 64 + lane];
  if (lane < 16){ d2 = pd[base + 128 + lane]; j2 = pi_[base + 128 + lane]; }
  #pragma unroll
  for (int s=0; s<9; s++){
    float ld = d0; int lj = j0;
    if (d1 < ld || (d1 == ld && j1 < lj)){ ld = d1; lj = j1; }
    if (d2 < ld || (d2 == ld && j2 < lj)){ ld = d2; lj = j2; }
    #pragma unroll
    for (int off=1; off<64; off<<=1){
      float od = __shfl_xor(ld, off, 64);
      int   oj = __shfl_xor(lj, off, 64);
      if (od < ld || (od == ld && oj < lj)){ ld = od; lj = oj; }
    }
    if (lane == 0) idxf[(size_t)row*9 + s] = lj & (NN-1);
    if (j0 == lj){ d0 = INFINITY; j0 = 0x7fffffff; }
    if (j1 == lj){ d1 = INFINITY; j1 = 0x7fffffff; }
    if (j2 == lj){ d2 = INFINITY; j2 = 0x7fffffff; }
  }
}

// ---------------- edge conv pass 1: stats only; 1024 blocks x 8 nodes ----------------
__global__ void k_edgestats(const float* __restrict__ h, const int* __restrict__ idxf,
                            const float* __restrict__ Wgf, const float* __restrict__ bg,
                            float* __restrict__ part){
  __shared__ float xiL[64];
  __shared__ float dxL[9*64];
  __shared__ int kidx[9];
  int tid = threadIdx.x;
  int c = tid;
  float bias = bg[c];
  float sm=0.f, ss=0.f;
  for (int u=0; u<8; u++){
    int node = blockIdx.x*8 + u;
    int b = node >> 12;
    __syncthreads();
    if (tid < 64) xiL[tid] = h[(size_t)node*64 + tid];
    if (tid < 9) kidx[tid] = idxf[(size_t)node*9 + tid] & (NN-1);
    __syncthreads();
    for (int r2 = tid; r2 < 9*64; r2 += 128){
      int k = r2 >> 6; int d = r2 & 63;
      dxL[r2] = h[((size_t)(b*NN + kidx[k]))*64 + d] - xiL[d];
    }
    __syncthreads();
    float common = bias;
    for (int d=0; d<64; d++) common = fmaf(xiL[d], Wgf[d*C2 + c], common);
    float acc[9];
    #pragma unroll
    for (int k=0;k<9;k++) acc[k]=0.f;
    for (int d=0; d<64; d++){
      float w = Wgf[(64+d)*C2 + c];
      #pragma unroll
      for (int k=0;k<9;k++) acc[k] = fmaf(dxL[k*64+d], w, acc[k]);
    }
    #pragma unroll
    for (int k=0;k<9;k++){ float v = common + acc[k]; sm += v; ss += v*v; }
  }
  part[blockIdx.x*256 + c] = sm;
  part[blockIdx.x*256 + 128 + c] = ss;
}

// ---------------- edge conv pass 2: 1024 blocks x 8 nodes ----------------
__global__ void k_edgemax3(const float* __restrict__ h, const int* __restrict__ idxf,
                           const float* __restrict__ Wgf, const float* __restrict__ bg,
                           const float* __restrict__ scsh, float* __restrict__ gmax){
  __shared__ float xiL[64];
  __shared__ float dxL[9*64];
  __shared__ int kidx[9];
  int tid = threadIdx.x;
  int c = tid;
  float bias = bg[c];
  float sc = scsh[c], sh = scsh[C2 + c];
  for (int u=0; u<8; u++){
    int node = blockIdx.x*8 + u;
    int b = node >> 12;
    __syncthreads();
    if (tid < 64) xiL[tid] = h[(size_t)node*64 + tid];
    if (tid < 9) kidx[tid] = idxf[(size_t)node*9 + tid] & (NN-1);
    __syncthreads();
    for (int r2 = tid; r2 < 9*64; r2 += 128){
      int k = r2 >> 6; int d = r2 & 63;
      dxL[r2] = h[((size_t)(b*NN + kidx[k]))*64 + d] - xiL[d];
    }
    __syncthreads();
    float common = bias;
    for (int d=0; d<64; d++) common = fmaf(xiL[d], Wgf[d*C2 + c], common);
    float acc[9];
    #pragma unroll
    for (int k=0;k<9;k++) acc[k]=0.f;
    for (int d=0; d<64; d++){
      float w = Wgf[(64+d)*C2 + c];
      #pragma unroll
      for (int k=0;k<9;k++) acc[k] = fmaf(dxL[k*64+d], w, acc[k]);
    }
    float m = -INFINITY;
    #pragma unroll
    for (int k=0;k<9;k++){
      float v = fmaf(common + acc[k], sc, sh);
      m = fmaxf(m, gelu(v));
    }
    gmax[(size_t)node*C2 + c] = m;
  }
}

// ---------------- BN2-apply + residual + FFN1 GEMM + stats: 512 x 16 rows ----------
__global__ void k_ffn1_fused(const float* __restrict__ Y2, const float* __restrict__ scsh,
                             const float* __restrict__ x0f, float* __restrict__ outt,
                             const float* __restrict__ Wf1, const float* __restrict__ bf1,
                             float* __restrict__ partB){
  __shared__ float scshL[128];
  __shared__ float otL[16*64];
  __shared__ float WL[64*256];
  int tid = threadIdx.x;
  int r0 = blockIdx.x*16;
  {
    const float4* s4 = (const float4*)Wf1; float4* d4 = (float4*)WL;
    #pragma unroll
    for (int u=0; u<16; u++) d4[u*256+tid] = s4[u*256+tid];
  }
  if (tid < 128) scshL[tid] = scsh[tid];
  __syncthreads();
  for (int p=0; p<4; p++){
    int idx = p*256 + tid;
    int lr = idx >> 6, cc = idx & 63;
    size_t gi = (size_t)(r0+lr)*64 + cc;
    float v = fmaf(Y2[gi], scshL[cc], scshL[64+cc]) + x0f[gi];
    otL[idx] = v; outt[gi] = v;
  }
  __syncthreads();
  float bias = bf1[tid];
  float sm=0.f, ss=0.f;
  for (int lr=0; lr<16; lr++){
    float acc = bias;
    for (int d=0; d<64; d++) acc = fmaf(otL[lr*64+d], WL[d*256+tid], acc);
    sm += acc; ss += acc*acc;
  }
  partB[blockIdx.x*512 + tid] = sm;
  partB[blockIdx.x*512 + 256 + tid] = ss;
}

// ------- BNf1-apply + FFN1-recompute + gelu + FFN2 GEMM + stats: 512 x 16 rows -------
__global__ void k_ffn2_fused(const float* __restrict__ outt, const float* __restrict__ Wf1,
                             const float* __restrict__ bf1, const float* __restrict__ scsh,
                             const float* __restrict__ Wf2, const float* __restrict__ bf2,
                             float* __restrict__ Yf2, float* __restrict__ partA){
  __shared__ float scshL[512];
  __shared__ float otL[16*64];
  __shared__ float fLL[16*256];
  __shared__ float s1[256], s2[256];
  int tid = threadIdx.x;
  int r0 = blockIdx.x*16;
  scshL[tid] = scsh[tid];
  scshL[256+tid] = scsh[256+tid];
  for (int p=0; p<4; p++){
    int idx = p*256 + tid;
    otL[idx] = outt[(size_t)r0*64 + idx];
  }
  __syncthreads();
  float bias = bf1[tid];
  for (int lr=0; lr<16; lr++){
    float acc = bias;
    for (int d=0; d<64; d++) acc = fmaf(otL[lr*64+d], Wf1[d*256+tid], acc);
    float v = fmaf(acc, scshL[tid], scshL[256+tid]);
    fLL[lr*256+tid] = gelu(v);
  }
  __syncthreads();
  int c = tid & 63, rs = tid >> 6;
  float b2z = bf2[c];
  float sm=0.f, ss=0.f;
  for (int it=0; it<4; it++){
    int lr = it*4 + rs;
    float acc = b2z;
    for (int d=0; d<256; d++) acc = fmaf(fLL[lr*256+d], Wf2[d*64+c], acc);
    Yf2[(size_t)(r0+lr)*64 + c] = acc;
    sm += acc; ss += acc*acc;
  }
  s1[tid]=sm; s2[tid]=ss;
  __syncthreads();
  if (tid < 64){
    sm = s1[tid]+s1[64+tid]+s1[128+tid]+s1[192+tid];
    ss = s2[tid]+s2[64+tid]+s2[128+tid]+s2[192+tid];
    partA[blockIdx.x*128 + tid] = sm;
    partA[blockIdx.x*128 + 64 + tid] = ss;
  }
}

// ---------------- BNf2-apply + residual -> feats[t]: 512 blocks ----------------
__global__ void k_final(const float* __restrict__ Yf2, const float* __restrict__ scsh,
                        const float* __restrict__ outt, float* __restrict__ feat){
  __shared__ float scshL[128];
  int tid = threadIdx.x;
  if (tid < 128) scshL[tid] = scsh[tid];
  __syncthreads();
  size_t base = (size_t)blockIdx.x*1024;
  for (int p=0; p<4; p++){
    size_t idx = base + p*256 + tid;
    int cc = idx & 63;
    feat[idx] = fmaf(Yf2[idx], scshL[cc], scshL[64+cc]) + outt[idx];
  }
}

// ---------------- alpha-mix + transpose -> output (T,B,C,N) fp32 ----------------
__global__ void k_mix(const float* __restrict__ f0, const float* __restrict__ f1,
                      const float* __restrict__ alpha, float* __restrict__ outv){
  int idx = blockIdx.x*256 + threadIdx.x;
  if (idx >= TT*BB*CCH*NN) return;
  int n = idx & (NN-1);
  int c = (idx >> 12) & 63;
  int b = (idx >> 18) & 1;
  int i = idx >> 19;
  float a0 = alpha[i*TT + 0];
  float a1 = alpha[i*TT + 1];
  size_t fi = ((size_t)(b*NN + n))*64 + c;
  outv[idx] = a0*f0[fi] + a1*f1[fi];
}

extern "C" void kernel_launch(void* const* d_in, const int* in_sizes, int n_in,
                              void* d_out, int out_size, void* d_ws, size_t ws_size,
                              hipStream_t stream){
  float* outp = (float*)d_out;

  static const int expect[22] = {
    524288, 8192, 128, 128, 128, 32768, 256, 256, 256, 16384, 128, 128, 128,
    32768, 512, 512, 512, 32768, 128, 128, 128, 4
  };
  bool ok = (n_in == 22) && (out_size == TT*BB*CCH*NN) &&
            (ws_size >= WS_TOTAL*sizeof(float));
  if (ok){
    for (int i=0;i<22;i++) if (in_sizes[i] != expect[i]) { ok = false; break; }
  }
  if (!ok){
    k_zero<<<(out_size+255)/256,256,0,stream>>>(outp, out_size);
    return;
  }

  const float* x   = (const float*)d_in[0];
  const float* W1  = (const float*)d_in[1];
  const float* b1  = (const float*)d_in[2];
  const float* g1  = (const float*)d_in[3];
  const float* bt1 = (const float*)d_in[4];
  const float* Wg  = (const float*)d_in[5];
  const float* bg  = (const float*)d_in[6];
  const float* gg  = (const float*)d_in[7];
  const float* btg = (const float*)d_in[8];
  const float* W2  = (const float*)d_in[9];
  const float* b2v = (const float*)d_in[10];
  const float* g2  = (const float*)d_in[11];
  const float* bt2 = (const float*)d_in[12];
  const float* Wf1 = (const float*)d_in[13];
  const float* bf1v= (const float*)d_in[14];
  const float* gf1 = (const float*)d_in[15];
  const float* btf1= (const float*)d_in[16];
  const float* Wf2 = (const float*)d_in[17];
  const float* bf2v= (const float*)d_in[18];
  const float* gf2 = (const float*)d_in[19];
  const float* btf2= (const float*)d_in[20];
  const float* alpha=(const float*)d_in[21];
  float* ws = (float*)d_ws;

  float* x0f  = ws + 0;
  float* hbuf = ws + 524288;
  float* xnb  = ws + 1048576;
  float* sqb  = ws + 1572864;
  float* partA= ws + 1581056;            // 131072 (gemm1/gemm2/ffn2 partials: <=512*128)
  float* scsh = ws + 1712128;            // 512
  int*   idxf = (int*)(ws + 1712640);
  float* f0   = ws + 1786368;
  float* f1b  = ws + 2310656;
  float* Rbig = ws + 2834944;            // 2359296
  float* pdist = Rbig;
  int*   pidx  = (int*)(Rbig + (size_t)R1*SPLIT*9);
  float* epart = Rbig;                   // edge partials 1024*256 (pdist dead after merge)
  float* gmaxb = Rbig;                   // 1048576 (written after epart consumed)
  float* outt  = Rbig + 1048576;         // 524288
  float* Y2    = Rbig + 1572864;         // 524288
  float* partB2= Rbig;                   // ffn1 partials 512*512 (gmaxb dead by then)
  float* Yf2   = Rbig;                   // 524288 (after partB2 consumed)

  k_transpose<<<2048,256,0,stream>>>(x, x0f);
  float* feats[2] = {f0, f1b};
  for (int t=0; t<TT; t++){
    k_gemm1_stats<<<512,256,0,stream>>>(x0f, W1 + t*CCH*CCH, b1 + t*64, hbuf, partA);
    k_finalize256<<<1,256,0,stream>>>(partA, 512, 64, g1 + t*64, bt1 + t*64, (float)R1, scsh);
    k_applynorm2<<<512,256,0,stream>>>(hbuf, scsh, xnb, sqb);
    k_knn<<<512,256,0,stream>>>(xnb, sqb, pdist, pidx);
    k_knnmerge<<<2048,256,0,stream>>>(pdist, pidx, idxf);
    k_edgestats<<<1024,128,0,stream>>>(hbuf, idxf, Wg + t*C2*C2, bg + t*C2, epart);
    k_finalize256<<<1,256,0,stream>>>(epart, 1024, 128, gg + t*C2, btg + t*C2, (float)RG, scsh);
    k_edgemax3<<<1024,128,0,stream>>>(hbuf, idxf, Wg + t*C2*C2, bg + t*C2, scsh, gmaxb);
    k_gemm2_stats<<<512,256,0,stream>>>(gmaxb, W2 + t*C2*CCH, b2v + t*64, Y2, partA);
    k_finalize256<<<1,256,0,stream>>>(partA, 512, 64, g2 + t*64, bt2 + t*64, (float)R1, scsh);
    k_ffn1_fused<<<512,256,0,stream>>>(Y2, scsh, x0f, outt, Wf1 + t*CCH*C4, bf1v + t*C4, partB2);
    k_finalize256<<<1,256,0,stream>>>(partB2, 512, 256, gf1 + t*C4, btf1 + t*C4, (float)R1, scsh);
    k_ffn2_fused<<<512,256,0,stream>>>(outt, Wf1 + t*CCH*C4, bf1v + t*C4, scsh,
                                       Wf2 + t*C4*CCH, bf2v + t*64, Yf2, partA);
    k_finalize256<<<1,256,0,stream>>>(partA, 512, 64, gf2 + t*64, btf2 + t*64, (float)R1, scsh);
    k_final<<<512,256,0,stream>>>(Yf2, scsh, outt, feats[t]);
  }
  k_mix<<<4096,256,0,stream>>>(f0, f1b, alpha, outp);
}

// Round 13
// 1529.519 us; speedup vs baseline: 1.5349x; 1.5349x over previous
//
#include <hip/hip_runtime.h>
#include <math.h>

#define BB 2
#define CCH 64
#define NN 4096
#define KK 9
#define TT 2
#define C2 128
#define C4 256
#define R1 (BB*NN)        /* 8192  */
#define RG (BB*NN*KK)     /* 73728 */
#define SPLIT 16
#define CHUNK (NN/SPLIT)  /* 256 */
#define JT 64             /* j-tile rows staged in LDS */

#define WS_TOTAL 5194240ull

__device__ __forceinline__ float gelu(float v){ return 0.5f*v*(1.f + erff(v*0.70710678118654752f)); }

__global__ void k_zero(float* __restrict__ o, int n){
  int i = blockIdx.x*256 + threadIdx.x;
  if (i < n) o[i] = 0.f;
}

// ---------------- transpose x (B,C,N) -> x0f (B,N,C) ----------------
__global__ void k_transpose(const float* __restrict__ x, float* __restrict__ x0f){
  int idx = blockIdx.x*256 + threadIdx.x;
  if (idx >= BB*NN*CCH) return;
  int c = idx & (CCH-1);
  int n = (idx >> 6) & (NN-1);
  int b = idx >> 18;
  x0f[idx] = x[(size_t)(b*CCH + c)*NN + n];
}

// ---------------- GEMM1 (64->64) + stats: 256 blocks x 32 rows (R10 shape) --------
__global__ void k_gemm1_stats(const float* __restrict__ X, const float* __restrict__ W,
                              const float* __restrict__ bias, float* __restrict__ Y,
                              float* __restrict__ part){
  __shared__ float WL[64*64];
  __shared__ float xL[32*64];
  __shared__ float s1[256], s2[256];
  int tid = threadIdx.x;
  int r0 = blockIdx.x*32;
  {
    const float4* ws4 = (const float4*)W;
    float4* wd4 = (float4*)WL;
    #pragma unroll
    for (int u=0; u<4; u++) wd4[u*256+tid] = ws4[u*256+tid];
    const float4* xs4 = (const float4*)(X + (size_t)r0*64);
    float4* xd4 = (float4*)xL;
    #pragma unroll
    for (int u=0; u<2; u++) xd4[u*256+tid] = xs4[u*256+tid];
  }
  __syncthreads();
  int c = tid & 63, rs = tid >> 6;
  float bz = bias[c];
  float sm=0.f, ss=0.f;
  for (int it=0; it<8; it++){
    int lr = it*4 + rs;
    float acc = bz;
    for (int d=0; d<64; d++) acc = fmaf(xL[lr*64+d], WL[d*64+c], acc);
    Y[(size_t)(r0+lr)*64 + c] = acc;
    sm += acc; ss += acc*acc;
  }
  s1[tid]=sm; s2[tid]=ss;
  __syncthreads();
  if (tid < 64){
    sm = s1[tid]+s1[64+tid]+s1[128+tid]+s1[192+tid];
    ss = s2[tid]+s2[64+tid]+s2[128+tid]+s2[192+tid];
    part[blockIdx.x*128 + tid] = sm;
    part[blockIdx.x*128 + 64 + tid] = ss;
  }
}

// ---------------- GEMM2 (128->64) + stats: 256 blocks x 32 rows (R10 shape) -------
__global__ void k_gemm2_stats(const float* __restrict__ X, const float* __restrict__ W,
                              const float* __restrict__ bias, float* __restrict__ Y,
                              float* __restrict__ part){
  __shared__ float WL[128*64];
  __shared__ float xL[32*128];
  __shared__ float s1[256], s2[256];
  int tid = threadIdx.x;
  int r0 = blockIdx.x*32;
  {
    const float4* ws4 = (const float4*)W;
    float4* wd4 = (float4*)WL;
    #pragma unroll
    for (int u=0; u<8; u++) wd4[u*256+tid] = ws4[u*256+tid];
    const float4* xs4 = (const float4*)(X + (size_t)r0*128);
    float4* xd4 = (float4*)xL;
    #pragma unroll
    for (int u=0; u<4; u++) xd4[u*256+tid] = xs4[u*256+tid];
  }
  __syncthreads();
  int c = tid & 63, rs = tid >> 6;
  float bz = bias[c];
  float sm=0.f, ss=0.f;
  for (int it=0; it<8; it++){
    int lr = it*4 + rs;
    float acc = bz;
    for (int d=0; d<128; d++) acc = fmaf(xL[lr*128+d], WL[d*64+c], acc);
    Y[(size_t)(r0+lr)*64 + c] = acc;
    sm += acc; ss += acc*acc;
  }
  s1[tid]=sm; s2[tid]=ss;
  __syncthreads();
  if (tid < 64){
    sm = s1[tid]+s1[64+tid]+s1[128+tid]+s1[192+tid];
    ss = s2[tid]+s2[64+tid]+s2[128+tid]+s2[192+tid];
    part[blockIdx.x*128 + tid] = sm;
    part[blockIdx.x*128 + 64 + tid] = ss;
  }
}

// ---------------- inline fin (G=256, Cc=64) + BN apply + row-normalize ------------
__global__ void k_applynorm3(float* __restrict__ h, const float* __restrict__ part,
                             const float* __restrict__ g, const float* __restrict__ bt,
                             float* __restrict__ xn, float* __restrict__ sq){
  __shared__ float scshL[128];
  __shared__ float s1[256], s2[256];
  int tid = threadIdx.x;
  {
    int c = tid & 63, sl = tid >> 6;
    float sm=0.f, ss=0.f;
    #pragma unroll 4
    for (int u=sl*64; u<sl*64+64; u++){ sm += part[u*128+c]; ss += part[u*128+64+c]; }
    s1[tid]=sm; s2[tid]=ss;
  }
  __syncthreads();
  if (tid < 64){
    float sm = s1[tid]+s1[64+tid]+s1[128+tid]+s1[192+tid];
    float ss = s2[tid]+s2[64+tid]+s2[128+tid]+s2[192+tid];
    float mean = sm/(float)R1;
    float var = fmaxf(ss/(float)R1 - mean*mean, 0.f);
    float sc = g[tid]*rsqrtf(var+1e-5f);
    scshL[tid] = sc; scshL[64+tid] = bt[tid] - mean*sc;
  }
  __syncthreads();
  int lane = tid & 63, w = tid >> 6;
  int r0 = blockIdx.x*32;
  for (int it=0; it<8; it++){
    int r = r0 + w*8 + it;
    float v = fmaf(h[(size_t)r*64+lane], scshL[lane], scshL[64+lane]);
    h[(size_t)r*64+lane] = v;
    float s2v = v*v;
    #pragma unroll
    for (int off=32; off; off>>=1) s2v += __shfl_xor(s2v, off, 64);
    float den = fmaxf(sqrtf(s2v), 1e-12f);
    float xv = v/den;
    xn[(size_t)r*64+lane] = xv;
    float t2 = xv*xv;
    #pragma unroll
    for (int off=32; off; off>>=1) t2 += __shfl_xor(t2, off, 64);
    if (lane==0) sq[r] = t2;
  }
}

// ---------------- top-9 streaming insert (strict <) ----------------
__device__ __forceinline__ void topk_insert(float d, int j, float* bd, int* bi,
                                            float& wd, int& wi){
  if (d < wd){
    bool done=false;
    #pragma unroll
    for (int q=0;q<9;q++){
      if (!done && bd[q]==wd && bi[q]==wi){ bd[q]=d; bi[q]=j; done=true; }
    }
    wd = bd[0]; wi = bi[0];
    #pragma unroll
    for (int q=1;q<9;q++){
      if (bd[q] > wd || (bd[q]==wd && bi[q] > wi)){ wd=bd[q]; wi=bi[q]; }
    }
  }
}

// ---------------- KNN (unchanged) ----------------
__global__ __launch_bounds__(256, 2) void k_knn(const float* __restrict__ xn,
                      const float* __restrict__ sq,
                      float* __restrict__ pd, int* __restrict__ pi_){
  __shared__ float xjL[JT*64];
  __shared__ float sqL[JT];
  int bx = blockIdx.x;
  if (bx >= 512) return;
  int b     = bx >> 8;
  int ib    = (bx >> 4) & 15;
  int split = bx & 15;
  int tid = threadIdx.x;
  const float* xb = xn + (size_t)b*NN*64;
  const float* sqb = sq + (size_t)b*NN;
  int i = ib*256 + tid;
  float4 xi[16];
  {
    const float4* p = (const float4*)(xb + (size_t)i*64);
    #pragma unroll
    for (int q=0;q<16;q++) xi[q] = p[q];
  }
  #pragma unroll
  for (int q=0;q<16;q++){
    asm volatile("" : "+v"(xi[q].x), "+v"(xi[q].y), "+v"(xi[q].z), "+v"(xi[q].w));
  }
  float sqi = sqb[i];
  float bd[9]; int bi[9];
  #pragma unroll
  for (int q=0;q<9;q++){ bd[q]=INFINITY; bi[q]=0x7fffffff; }
  float wd=INFINITY; int wi=0x7fffffff;
  int jbase = split*CHUNK;
  for (int tile=0; tile<CHUNK/JT; tile++){
    int jt = jbase + tile*JT;
    __syncthreads();
    {
      const float4* src = (const float4*)(xb + (size_t)jt*64);
      float4* dst = (float4*)xjL;
      #pragma unroll
      for (int u=0; u<4; u++) dst[u*256 + tid] = src[u*256 + tid];
      if (tid < JT) sqL[tid] = sqb[jt + tid];
    }
    __syncthreads();
    for (int jj=0; jj<JT; jj++){
      const float4* xj = (const float4*)(xjL + jj*64);
      float a0=0.f,a1=0.f,a2=0.f,a3=0.f;
      #pragma unroll
      for (int q=0;q<16;q++){
        float4 v = xj[q];
        a0 = fmaf(xi[q].x, v.x, a0);
        a1 = fmaf(xi[q].y, v.y, a1);
        a2 = fmaf(xi[q].z, v.z, a2);
        a3 = fmaf(xi[q].w, v.w, a3);
      }
      float dot = (a0+a1)+(a2+a3);
      int j = jt + jj;
      float d = sqi + sqL[jj] - 2.f*dot;
      topk_insert(d, j, bd, bi, wd, wi);
    }
  }
  size_t base = (((size_t)(b*NN + i))*SPLIT + split)*9;
  #pragma unroll
  for (int q=0;q<9;q++){ pd[base+q]=bd[q]; pi_[base+q]=bi[q]; }
}

// ------- edge pass 1: fused merge + edge-GEMM stats; wave-private, barrier-free -----
// 512 blocks x 256 threads; 16 nodes/block, 4 nodes/wave.
__global__ __launch_bounds__(256) void k_edge1(const float* __restrict__ h,
                        const float* __restrict__ pd, const int* __restrict__ pi_,
                        const float* __restrict__ Wg, const float* __restrict__ bg,
                        int* __restrict__ idxf, float* __restrict__ part){
  __shared__ float dxAll[4*576];
  __shared__ float xiAll[4*64];
  __shared__ float sSum[512], sSq[512];
  int tid = threadIdx.x, lane = tid & 63, wv = tid >> 6;
  float* dxW = dxAll + wv*576;
  float* xiW = xiAll + wv*64;
  int c0 = lane, c1 = lane + 64;
  float bias0 = bg[c0], bias1 = bg[c1];
  float sm0=0.f, ss0=0.f, sm1=0.f, ss1=0.f;
  for (int u4=0; u4<4; u4++){
    int node = blockIdx.x*16 + wv*4 + u4;
    int b = node >> 12;
    // --- merge this node's 144 candidates -> 9 lex-smallest (all lanes get result) ---
    size_t cb = (size_t)node*(SPLIT*9);
    float d0 = pd[cb+lane], d1 = pd[cb+64+lane], d2 = INFINITY;
    int   j0 = pi_[cb+lane], j1 = pi_[cb+64+lane], j2 = 0x7fffffff;
    if (lane < 16){ d2 = pd[cb+128+lane]; j2 = pi_[cb+128+lane]; }
    int kidx[9];
    #pragma unroll
    for (int s=0; s<9; s++){
      float ld = d0; int lj = j0;
      if (d1 < ld || (d1 == ld && j1 < lj)){ ld = d1; lj = j1; }
      if (d2 < ld || (d2 == ld && j2 < lj)){ ld = d2; lj = j2; }
      #pragma unroll
      for (int off=1; off<64; off<<=1){
        float od = __shfl_xor(ld, off, 64);
        int   oj = __shfl_xor(lj, off, 64);
        if (od < ld || (od == ld && oj < lj)){ ld = od; lj = oj; }
      }
      kidx[s] = lj & (NN-1);
      if (lane == 0) idxf[(size_t)node*9 + s] = lj & (NN-1);
      if (j0 == lj){ d0 = INFINITY; j0 = 0x7fffffff; }
      if (j1 == lj){ d1 = INFINITY; j1 = 0x7fffffff; }
      if (j2 == lj){ d2 = INFINITY; j2 = 0x7fffffff; }
    }
    // --- gather (wave-private LDS slice; no block barrier) ---
    float xi_l = h[(size_t)node*64 + lane];
    xiW[lane] = xi_l;
    #pragma unroll
    for (int k=0; k<9; k++)
      dxW[k*64+lane] = h[((size_t)(b*NN + kidx[k]))*64 + lane] - xi_l;
    // --- compute: lane owns columns c0, c1 ---
    float common0 = bias0, common1 = bias1;
    for (int d=0; d<64; d++){
      float xv = xiW[d];
      common0 = fmaf(xv, Wg[d*C2+c0], common0);
      common1 = fmaf(xv, Wg[d*C2+c1], common1);
    }
    float a0[9], a1[9];
    #pragma unroll
    for (int k=0;k<9;k++){ a0[k]=0.f; a1[k]=0.f; }
    for (int d=0; d<64; d++){
      float w0 = Wg[(64+d)*C2+c0], w1 = Wg[(64+d)*C2+c1];
      #pragma unroll
      for (int k=0;k<9;k++){
        float dxv = dxW[k*64+d];
        a0[k] = fmaf(dxv, w0, a0[k]);
        a1[k] = fmaf(dxv, w1, a1[k]);
      }
    }
    #pragma unroll
    for (int k=0;k<9;k++){
      float v0 = common0 + a0[k], v1 = common1 + a1[k];
      sm0 += v0; ss0 += v0*v0; sm1 += v1; ss1 += v1*v1;
    }
  }
  sSum[wv*128+lane] = sm0; sSum[wv*128+64+lane] = sm1;
  sSq [wv*128+lane] = ss0; sSq [wv*128+64+lane] = ss1;
  __syncthreads();
  if (tid < 128){
    float sm = sSum[tid]+sSum[128+tid]+sSum[256+tid]+sSum[384+tid];
    float ss = sSq[tid]+sSq[128+tid]+sSq[256+tid]+sSq[384+tid];
    part[blockIdx.x*256 + tid] = sm;
    part[blockIdx.x*256 + 128 + tid] = ss;
  }
}

// ------- edge pass 2: inline fin (G=512,Cc=128) + recompute + BN + gelu + max ------
__global__ __launch_bounds__(256) void k_edge2(const float* __restrict__ h,
                        const int* __restrict__ idxf,
                        const float* __restrict__ Wg, const float* __restrict__ bg,
                        const float* __restrict__ part, const float* __restrict__ gg,
                        const float* __restrict__ btg, float* __restrict__ gmax){
  __shared__ float dxAll[4*576];
  __shared__ float xiAll[4*64];
  __shared__ float scshL[256];
  __shared__ float s1[256], s2[256];
  int tid = threadIdx.x, lane = tid & 63, wv = tid >> 6;
  {
    int cc = tid & 127, sl = tid >> 7;
    float sm=0.f, ss=0.f;
    #pragma unroll 4
    for (int u=sl*256; u<sl*256+256; u++){ sm += part[u*256+cc]; ss += part[u*256+128+cc]; }
    s1[tid]=sm; s2[tid]=ss;
  }
  __syncthreads();
  if (tid < 128){
    float sm = s1[tid]+s1[128+tid];
    float ss = s2[tid]+s2[128+tid];
    float mean = sm/(float)RG;
    float var = fmaxf(ss/(float)RG - mean*mean, 0.f);
    float sc = gg[tid]*rsqrtf(var+1e-5f);
    scshL[tid] = sc; scshL[128+tid] = btg[tid] - mean*sc;
  }
  __syncthreads();
  float* dxW = dxAll + wv*576;
  float* xiW = xiAll + wv*64;
  int c0 = lane, c1 = lane + 64;
  float bias0 = bg[c0], bias1 = bg[c1];
  float sc0 = scshL[c0], sh0 = scshL[128+c0];
  float sc1 = scshL[c1], sh1 = scshL[128+c1];
  for (int u4=0; u4<4; u4++){
    int node = blockIdx.x*16 + wv*4 + u4;
    int b = node >> 12;
    int kidx[9];
    #pragma unroll
    for (int k=0;k<9;k++) kidx[k] = idxf[(size_t)node*9 + k] & (NN-1);
    float xi_l = h[(size_t)node*64 + lane];
    xiW[lane] = xi_l;
    #pragma unroll
    for (int k=0; k<9; k++)
      dxW[k*64+lane] = h[((size_t)(b*NN + kidx[k]))*64 + lane] - xi_l;
    float common0 = bias0, common1 = bias1;
    for (int d=0; d<64; d++){
      float xv = xiW[d];
      common0 = fmaf(xv, Wg[d*C2+c0], common0);
      common1 = fmaf(xv, Wg[d*C2+c1], common1);
    }
    float a0[9], a1[9];
    #pragma unroll
    for (int k=0;k<9;k++){ a0[k]=0.f; a1[k]=0.f; }
    for (int d=0; d<64; d++){
      float w0 = Wg[(64+d)*C2+c0], w1 = Wg[(64+d)*C2+c1];
      #pragma unroll
      for (int k=0;k<9;k++){
        float dxv = dxW[k*64+d];
        a0[k] = fmaf(dxv, w0, a0[k]);
        a1[k] = fmaf(dxv, w1, a1[k]);
      }
    }
    float m0 = -INFINITY, m1 = -INFINITY;
    #pragma unroll
    for (int k=0;k<9;k++){
      m0 = fmaxf(m0, gelu(fmaf(common0 + a0[k], sc0, sh0)));
      m1 = fmaxf(m1, gelu(fmaf(common1 + a1[k], sc1, sh1)));
    }
    gmax[(size_t)node*C2 + c0] = m0;
    gmax[(size_t)node*C2 + c1] = m1;
  }
}

// ------- inline fin(G=256,Cc=64) + BN2 + residual + FFN1 GEMM + stats --------------
__global__ void k_ffn1_fused(const float* __restrict__ Y2, const float* __restrict__ part,
                             const float* __restrict__ g2, const float* __restrict__ bt2,
                             const float* __restrict__ x0f, float* __restrict__ outt,
                             const float* __restrict__ Wf1, const float* __restrict__ bf1,
                             float* __restrict__ partB){
  __shared__ float scshL[128];
  __shared__ float otL[32*64];
  __shared__ float WL[64*256];
  __shared__ float s1[256], s2[256];
  int tid = threadIdx.x;
  int r0 = blockIdx.x*32;
  {
    const float4* s4 = (const float4*)Wf1; float4* d4 = (float4*)WL;
    #pragma unroll
    for (int u=0; u<16; u++) d4[u*256+tid] = s4[u*256+tid];
  }
  {
    int c = tid & 63, sl = tid >> 6;
    float sm=0.f, ss=0.f;
    #pragma unroll 4
    for (int u=sl*64; u<sl*64+64; u++){ sm += part[u*128+c]; ss += part[u*128+64+c]; }
    s1[tid]=sm; s2[tid]=ss;
  }
  __syncthreads();
  if (tid < 64){
    float sm = s1[tid]+s1[64+tid]+s1[128+tid]+s1[192+tid];
    float ss = s2[tid]+s2[64+tid]+s2[128+tid]+s2[192+tid];
    float mean = sm/(float)R1;
    float var = fmaxf(ss/(float)R1 - mean*mean, 0.f);
    float sc = g2[tid]*rsqrtf(var+1e-5f);
    scshL[tid] = sc; scshL[64+tid] = bt2[tid] - mean*sc;
  }
  __syncthreads();
  for (int p=0; p<8; p++){
    int idx = p*256 + tid;
    int lr = idx >> 6, cc = idx & 63;
    size_t gi = (size_t)(r0+lr)*64 + cc;
    float v = fmaf(Y2[gi], scshL[cc], scshL[64+cc]) + x0f[gi];
    otL[idx] = v; outt[gi] = v;
  }
  __syncthreads();
  float bias = bf1[tid];
  float sm=0.f, ss=0.f;
  for (int lr=0; lr<32; lr++){
    float acc = bias;
    for (int d=0; d<64; d++) acc = fmaf(otL[lr*64+d], WL[d*256+tid], acc);
    sm += acc; ss += acc*acc;
  }
  partB[blockIdx.x*512 + tid] = sm;
  partB[blockIdx.x*512 + 256 + tid] = ss;
}

// ------- inline fin(G=256,Cc=256) + FFN1-recompute + gelu + FFN2 GEMM + stats ------
__global__ void k_ffn2_fused(const float* __restrict__ outt, const float* __restrict__ Wf1,
                             const float* __restrict__ bf1, const float* __restrict__ partB,
                             const float* __restrict__ gf1, const float* __restrict__ btf1,
                             const float* __restrict__ Wf2, const float* __restrict__ bf2,
                             float* __restrict__ Yf2, float* __restrict__ partA){
  __shared__ float scshL[512];
  __shared__ float otL[32*64];
  __shared__ float fLL[32*256];
  __shared__ float s1[256], s2[256];
  int tid = threadIdx.x;
  int r0 = blockIdx.x*32;
  {
    float sm=0.f, ss=0.f;
    #pragma unroll 4
    for (int u=0; u<256; u++){ sm += partB[u*512+tid]; ss += partB[u*512+256+tid]; }
    float mean = sm/(float)R1;
    float var = fmaxf(ss/(float)R1 - mean*mean, 0.f);
    float sc = gf1[tid]*rsqrtf(var+1e-5f);
    scshL[tid] = sc; scshL[256+tid] = btf1[tid] - mean*sc;
  }
  for (int p=0; p<8; p++){
    int idx = p*256 + tid;
    otL[idx] = outt[(size_t)r0*64 + idx];
  }
  __syncthreads();
  float bias = bf1[tid];
  for (int lr=0; lr<32; lr++){
    float acc = bias;
    for (int d=0; d<64; d++) acc = fmaf(otL[lr*64+d], Wf1[d*256+tid], acc);
    float v = fmaf(acc, scshL[tid], scshL[256+tid]);
    fLL[lr*256+tid] = gelu(v);
  }
  __syncthreads();
  int c = tid & 63, rs = tid >> 6;
  float b2z = bf2[c];
  float sm=0.f, ss=0.f;
  for (int it=0; it<8; it++){
    int lr = it*4 + rs;
    float acc = b2z;
    for (int d=0; d<256; d++) acc = fmaf(fLL[lr*256+d], Wf2[d*64+c], acc);
    Yf2[(size_t)(r0+lr)*64 + c] = acc;
    sm += acc; ss += acc*acc;
  }
  s1[tid]=sm; s2[tid]=ss;
  __syncthreads();
  if (tid < 64){
    sm = s1[tid]+s1[64+tid]+s1[128+tid]+s1[192+tid];
    ss = s2[tid]+s2[64+tid]+s2[128+tid]+s2[192+tid];
    partA[blockIdx.x*128 + tid] = sm;
    partA[blockIdx.x*128 + 64 + tid] = ss;
  }
}

// ---------------- inline fin(G=256,Cc=64) + BNf2 + residual -> feats[t] ------------
__global__ void k_final(const float* __restrict__ Yf2, const float* __restrict__ partA,
                        const float* __restrict__ gf2, const float* __restrict__ btf2,
                        const float* __restrict__ outt, float* __restrict__ feat){
  __shared__ float scshL[128];
  __shared__ float s1[256], s2[256];
  int tid = threadIdx.x;
  {
    int c = tid & 63, sl = tid >> 6;
    float sm=0.f, ss=0.f;
    #pragma unroll 4
    for (int u=sl*64; u<sl*64+64; u++){ sm += partA[u*128+c]; ss += partA[u*128+64+c]; }
    s1[tid]=sm; s2[tid]=ss;
  }
  __syncthreads();
  if (tid < 64){
    float sm = s1[tid]+s1[64+tid]+s1[128+tid]+s1[192+tid];
    float ss = s2[tid]+s2[64+tid]+s2[128+tid]+s2[192+tid];
    float mean = sm/(float)R1;
    float var = fmaxf(ss/(float)R1 - mean*mean, 0.f);
    float sc = gf2[tid]*rsqrtf(var+1e-5f);
    scshL[tid] = sc; scshL[64+tid] = btf2[tid] - mean*sc;
  }
  __syncthreads();
  size_t base = (size_t)blockIdx.x*2048;
  for (int p=0; p<8; p++){
    size_t idx = base + p*256 + tid;
    int cc = idx & 63;
    feat[idx] = fmaf(Yf2[idx], scshL[cc], scshL[64+cc]) + outt[idx];
  }
}

// ---------------- alpha-mix + transpose -> output (T,B,C,N) fp32 ----------------
__global__ void k_mix(const float* __restrict__ f0, const float* __restrict__ f1,
                      const float* __restrict__ alpha, float* __restrict__ outv){
  int idx = blockIdx.x*256 + threadIdx.x;
  if (idx >= TT*BB*CCH*NN) return;
  int n = idx & (NN-1);
  int c = (idx >> 12) & 63;
  int b = (idx >> 18) & 1;
  int i = idx >> 19;
  float a0 = alpha[i*TT + 0];
  float a1 = alpha[i*TT + 1];
  size_t fi = ((size_t)(b*NN + n))*64 + c;
  outv[idx] = a0*f0[fi] + a1*f1[fi];
}

extern "C" void kernel_launch(void* const* d_in, const int* in_sizes, int n_in,
                              void* d_out, int out_size, void* d_ws, size_t ws_size,
                              hipStream_t stream){
  float* outp = (float*)d_out;

  static const int expect[22] = {
    524288, 8192, 128, 128, 128, 32768, 256, 256, 256, 16384, 128, 128, 128,
    32768, 512, 512, 512, 32768, 128, 128, 128, 4
  };
  bool ok = (n_in == 22) && (out_size == TT*BB*CCH*NN) &&
            (ws_size >= WS_TOTAL*sizeof(float));
  if (ok){
    for (int i=0;i<22;i++) if (in_sizes[i] != expect[i]) { ok = false; break; }
  }
  if (!ok){
    k_zero<<<(out_size+255)/256,256,0,stream>>>(outp, out_size);
    return;
  }

  const float* x   = (const float*)d_in[0];
  const float* W1  = (const float*)d_in[1];
  const float* b1  = (const float*)d_in[2];
  const float* g1  = (const float*)d_in[3];
  const float* bt1 = (const float*)d_in[4];
  const float* Wg  = (const float*)d_in[5];
  const float* bg  = (const float*)d_in[6];
  const float* gg  = (const float*)d_in[7];
  const float* btg = (const float*)d_in[8];
  const float* W2  = (const float*)d_in[9];
  const float* b2v = (const float*)d_in[10];
  const float* g2  = (const float*)d_in[11];
  const float* bt2 = (const float*)d_in[12];
  const float* Wf1 = (const float*)d_in[13];
  const float* bf1v= (const float*)d_in[14];
  const float* gf1 = (const float*)d_in[15];
  const float* btf1= (const float*)d_in[16];
  const float* Wf2 = (const float*)d_in[17];
  const float* bf2v= (const float*)d_in[18];
  const float* gf2 = (const float*)d_in[19];
  const float* btf2= (const float*)d_in[20];
  const float* alpha=(const float*)d_in[21];
  float* ws = (float*)d_ws;

  float* x0f  = ws + 0;
  float* hbuf = ws + 524288;
  float* xnb  = ws + 1048576;
  float* sqb  = ws + 1572864;
  float* partA= ws + 1581056;            // 131072 floats
  int*   idxf = (int*)(ws + 1712640);
  float* f0   = ws + 1786368;
  float* f1b  = ws + 2310656;
  float* Rbig = ws + 2834944;            // 2359296 floats
  float* pdist = Rbig;                   // R1*144
  int*   pidx  = (int*)(Rbig + (size_t)R1*SPLIT*9);
  float* gmaxb = Rbig;                   // 1048576 (pd/pi dead after edge1)
  float* outt  = Rbig + 1048576;         // 524288
  float* Y2    = Rbig + 1572864;         // 524288
  float* partB = Rbig + 2097152;         // 131072 (ffn1 partials)
  float* Yf2   = Rbig;                   // 524288 (gmax dead after gemm2)

  k_transpose<<<2048,256,0,stream>>>(x, x0f);
  float* feats[2] = {f0, f1b};
  for (int t=0; t<TT; t++){
    k_gemm1_stats<<<256,256,0,stream>>>(x0f, W1 + t*CCH*CCH, b1 + t*64, hbuf, partA);
    k_applynorm3<<<256,256,0,stream>>>(hbuf, partA, g1 + t*64, bt1 + t*64, xnb, sqb);
    k_knn<<<512,256,0,stream>>>(xnb, sqb, pdist, pidx);
    k_edge1<<<512,256,0,stream>>>(hbuf, pdist, pidx, Wg + t*C2*C2, bg + t*C2, idxf, partA);
    k_edge2<<<512,256,0,stream>>>(hbuf, idxf, Wg + t*C2*C2, bg + t*C2,
                                  partA, gg + t*C2, btg + t*C2, gmaxb);
    k_gemm2_stats<<<256,256,0,stream>>>(gmaxb, W2 + t*C2*CCH, b2v + t*64, Y2, partA);
    k_ffn1_fused<<<256,256,0,stream>>>(Y2, partA, g2 + t*64, bt2 + t*64, x0f, outt,
                                       Wf1 + t*CCH*C4, bf1v + t*C4, partB);
    k_ffn2_fused<<<256,256,0,stream>>>(outt, Wf1 + t*CCH*C4, bf1v + t*C4, partB,
                                       gf1 + t*C4, btf1 + t*C4,
                                       Wf2 + t*C4*CCH, bf2v + t*64, Yf2, partA);
    k_final<<<256,256,0,stream>>>(Yf2, partA, gf2 + t*64, btf2 + t*64, outt, feats[t]);
  }
  k_mix<<<4096,256,0,stream>>>(f0, f1b, alpha, outp);
}